// Round 4
// baseline (460.827 us; speedup 1.0000x reference)
//
#include <hip/hip_runtime.h>
#include <math.h>

namespace {
constexpr int D     = 192;
constexpr int HW    = 256 * 512;   // 131072 = 2^17
constexpr int TOTAL = 2 * HW;      // 262144 pixels
constexpr unsigned ROWB = (unsigned)HW * 4u;   // bytes per depth slice (512 KB)

// Correctly-rounded s/5 in 3 ops (Markstein): bit-exact vs IEEE s/5.0f for
// all normal s >= 0 (our s in [0,5)).
__device__ __forceinline__ float div5(float s) {
    const float c = 0.2f;
    float q = s * c;
    float r = __builtin_fmaf(-5.0f, q, s);
    return __builtin_fmaf(r, c, q);
}

// Uniform SGPR base + 32-bit byte offset -> global_load v, voff, s[base]
__device__ __forceinline__ float ldx(const float* __restrict__ xn, unsigned bo) {
    return *reinterpret_cast<const float*>(
               reinterpret_cast<const char*>(xn) + bo);
}

__device__ __forceinline__ bool in_range(int d, int lo, unsigned wd) {
    return (unsigned)(d - lo) <= wd;
}

// Streaming modal-mask state machine, bit-exact vs the numpy reference.
// (Identical to the verified 139 us round-0 kernel.)
struct Machine {
    float bprev, maxv;
    int   index, last_fall, index_l, index_r;
    bool  r_found;

    __device__ __forceinline__ void init() {
        bprev = 1.0f;          // "ones" prepend: diff at d=0 is b0 - 1 < 0 -> fall
        maxv  = -INFINITY;
        index = 0; last_fall = 0; index_l = 0;
        index_r = D - 1;       // default: rise at virtual position D (append ones)
        r_found = false;
    }

    __device__ __forceinline__ void step(int d, float b) {
        float diff = b - bprev;
        bool fall  = diff < 0.0f;
        last_fall  = fall ? d : last_fall;               // strict fall
        bool am    = b > maxv;                           // first-occurrence argmax
        maxv       = am ? b : maxv;
        index      = am ? d : index;
        index_l    = am ? last_fall : index_l;           // last fall <= new argmax
        bool rise  = (diff > 0.0f) & (!r_found) & (!am); // first strict rise AFTER argmax
        index_r    = am ? (D - 1) : (rise ? (d - 1) : index_r);
        r_found    = am ? false : (r_found | rise);
        bprev      = b;
    }

    __device__ __forceinline__ void finish(int& lo, unsigned& wd) const {
        int r = min(index_r - index, index - index_l);
        int t = 2 * index - index_r - index_l;
        bool valid = (t > -3) && (t < 3);
        lo = valid ? index_l : (index - r);
        int hi = valid ? index_r : (index + r);
        wd = (unsigned)(hi - lo);
    }
};

// Load chunk c (8 consecutive depths) from byte base vo4 (= hw4 + OFS*ROWB).
// NG < 8 zero-fills the tail (absolute depth >= D guard, last chunk of the
// lookahead stream only: depths 192,193 are reference zero-padding AND would
// read past image 1's buffer end).
template<int NG>
__device__ __forceinline__ void ld8(const float* __restrict__ xn, unsigned vo4,
                                    int c, float (&buf)[8]) {
    #pragma unroll
    for (int j = 0; j < 8; ++j)
        buf[j] = (j < NG) ? ldx(xn, vo4 + (unsigned)(8 * c + j) * ROWB) : 0.0f;
}

// 24 chunks of 8 depths, SIX-buffer rotating software pipeline: constant
// FIVE-chunk load->use distance (~40 steps ~ 1600+ cyc of VALU between issue
// and wait), comfortably covering the ~900 cyc HBM-miss latency that capped
// the 3-buffer version at 49% VALUBusy. The grid pins occupancy at 4
// waves/SIMD (16/CU), so the extra ~48 VGPRs of in-flight data are free:
// anything <=128 VGPR keeps the same occupancy.
template<int LASTN, typename F>
__device__ __forceinline__ void stream24(const float* __restrict__ xn,
                                         unsigned vo4, F&& f) {
    float A[8], B[8], C[8], Dv[8], E[8], Fv[8];
    ld8<8>(xn, vo4, 0, A);
    ld8<8>(xn, vo4, 1, B);
    ld8<8>(xn, vo4, 2, C);
    ld8<8>(xn, vo4, 3, Dv);
    ld8<8>(xn, vo4, 4, E);
    ld8<8>(xn, vo4, 5, Fv);
    int d = 0;
    auto comp = [&](float (&buf)[8]) {
        #pragma unroll
        for (int j = 0; j < 8; ++j) { f(d, buf[j]); ++d; }
    };
    // g=0: compute chunks 0-5, issue 6-11
    comp(A);  ld8<8>(xn, vo4, 6, A);
    comp(B);  ld8<8>(xn, vo4, 7, B);
    comp(C);  ld8<8>(xn, vo4, 8, C);
    comp(Dv); ld8<8>(xn, vo4, 9, Dv);
    comp(E);  ld8<8>(xn, vo4, 10, E);
    comp(Fv); ld8<8>(xn, vo4, 11, Fv);
    // g=1: compute 6-11, issue 12-17
    comp(A);  ld8<8>(xn, vo4, 12, A);
    comp(B);  ld8<8>(xn, vo4, 13, B);
    comp(C);  ld8<8>(xn, vo4, 14, C);
    comp(Dv); ld8<8>(xn, vo4, 15, Dv);
    comp(E);  ld8<8>(xn, vo4, 16, E);
    comp(Fv); ld8<8>(xn, vo4, 17, Fv);
    // g=2: compute 12-17, issue 18-23 (23 tail-guarded in lookahead mode)
    comp(A);  ld8<8>(xn, vo4, 18, A);
    comp(B);  ld8<8>(xn, vo4, 19, B);
    comp(C);  ld8<8>(xn, vo4, 20, C);
    comp(Dv); ld8<8>(xn, vo4, 21, Dv);
    comp(E);  ld8<8>(xn, vo4, 22, E);
    comp(Fv); ld8<LASTN>(xn, vo4, 23, Fv);
    // drain: compute 18-23
    comp(A); comp(B); comp(C); comp(Dv); comp(E); comp(Fv);
}
} // namespace

// (256,4): cap 128 VGPR = the 4-waves/SIMD bucket the 4096-wave grid already
// pins us to. Do NOT use (256,8): it hard-caps at 64 and caused a 280
// MB/dispatch scratch-spill spiral in an earlier round.
extern "C" __global__ void __launch_bounds__(256, 4)
dme_kernel(const float* __restrict__ x, float* __restrict__ out)
{
    // n is block-uniform: 512 blocks per image -> base pointer lives in SGPRs.
    const int n  = blockIdx.x >> 9;
    const int hw = ((blockIdx.x & 511) << 8) | threadIdx.x;
    const float* __restrict__ xn = x + (size_t)n * ((size_t)D * HW);
    const unsigned hw4 = (unsigned)hw * 4u;

    const float x0 = ldx(xn, hw4);
    const float x1 = ldx(xn, hw4 + ROWB);

    // ================= pass 1: modal mask of blur(x) =================
    Machine m1; m1.init();
    {
        float w0 = 0.f, w1 = 0.f, w2 = x0, w3 = x1;
        stream24<6>(xn, hw4 + 2u * ROWB, [&](int d, float xv) {
            // exact left-to-right window sum, matching reference add order
            float s = w0 + w1; s += w2; s += w3; s += xv;
            m1.step(d, div5(s));
            w0 = w1; w1 = w2; w2 = w3; w3 = xv;
        });
    }
    int lo1; unsigned wd1; m1.finish(lo1, wd1);

    // ====== pass 2: modal mask of blur(x)*~mask1, plus y-sums ======
    Machine m2; m2.init();
    float sum_y = 0.f, wsum_y = 0.f;
    {
        float w0 = 0.f, w1 = 0.f, w2 = x0, w3 = x1;
        stream24<6>(xn, hw4 + 2u * ROWB, [&](int d, float xv) {
            float s = w0 + w1; s += w2; s += w3; s += xv;
            float b = div5(s);
            bool in1 = in_range(d, lo1, wd1);
            m2.step(d, in1 ? 0.0f : b);          // x_blur2 = x_blur * ~mask1
            float xm = in1 ? w2 : 0.0f;          // y = x*mask1; x[d] == w2
            sum_y += xm;
            wsum_y = __builtin_fmaf(xm, (float)d, wsum_y);
            w0 = w1; w1 = w2; w2 = w3; w3 = xv;
        });
    }
    int lo2; unsigned wd2; m2.finish(lo2, wd2);

    // ========= pass 3: z-sums (z = x * ~mask1 * mask2nd) =========
    float sum_z = 0.f, wsum_z = 0.f;
    {
        stream24<8>(xn, hw4, [&](int d, float xv) {
            bool z = in_range(d, lo2, wd2) & !in_range(d, lo1, wd1);
            float xm = z ? xv : 0.0f;
            sum_z += xm;
            wsum_z = __builtin_fmaf(xm, (float)d, wsum_z);
        });
    }

    bool  v = (sum_y >= sum_z);
    float S = v ? sum_y  : sum_z;
    float W = v ? wsum_y : wsum_z;
    out[hw + n * HW] = W / S;    // == sum(xm*d)/sum(xm)
}

extern "C" void kernel_launch(void* const* d_in, const int* in_sizes, int n_in,
                              void* d_out, int out_size, void* d_ws, size_t ws_size,
                              hipStream_t stream)
{
    const float* x   = (const float*)d_in[0];
    float*       out = (float*)d_out;
    dim3 block(256), grid(TOTAL / 256);          // 1024 blocks, 16 waves/CU
    hipLaunchKernelGGL(dme_kernel, grid, block, 0, stream, x, out);
}